// Round 8
// baseline (974.440 us; speedup 1.0000x reference)
//
#include <hip/hip_runtime.h>

#define PTOT  16384
#define CCC   512
#define HHH   8
#define NK1   32                 /* k1: 512/16 k-steps */
#define NK2   16                 /* k2: 512/32 k-steps */

typedef __attribute__((ext_vector_type(4)))  float f32x4;
typedef __attribute__((ext_vector_type(16))) float f32x16;
typedef _Float16 half_t;
typedef __attribute__((ext_vector_type(8))) _Float16 f16x8;

#define MFMA16(a,b,c) __builtin_amdgcn_mfma_f32_16x16x32_f16(a,b,c,0,0,0)
#define MFMA32(a,b,c) __builtin_amdgcn_mfma_f32_32x32x16_f16(a,b,c,0,0,0)

// ---- ws plane layout (half elements) ----
#define XH_OFF   ((size_t)0)
#define XL_OFF   ((size_t)33554432)
#define ACT_OFF  ((size_t)67108864)
#define W_OFF    ((size_t)100663296)
#define WPL      ((size_t)262144)
// W plane order: 0 qh, 1 ql, 2 kh, 3 kl, 4 vh, 5 oh

// 16-row frag layout (act plane + Wo plane; k2 consumes via 16x16x32 MFMA)
__device__ __forceinline__ size_t blk_off16(int row, int col) {
    return ((size_t)((row >> 4) * 16 + (col >> 5)) << 9)
         + (size_t)(((((col >> 3) & 3) * 16) + (row & 15)) << 3) + (col & 7);
}

// ---------------------------------------------------------------------------
// k0: split fp32 -> fp16 hi/lo planes (unchanged from round 6/7).
// ---------------------------------------------------------------------------
__global__ void k0_split(const float* __restrict__ x,
                         const float* __restrict__ Wq, const float* __restrict__ Wk,
                         const float* __restrict__ Wv, const float* __restrict__ Wo,
                         half_t* __restrict__ ws)
{
    const int u = blockIdx.x * 256 + threadIdx.x;   // 4,325,376 threads
    if (u < 4194304) {                              // ---- x region ----
        const int f = u >> 6, lane6 = u & 63;
        const int grow32 = f >> 5, ktc = f & 31;
        const int row = grow32 * 32 + (lane6 & 31);
        const int k   = ktc * 16 + (lane6 >> 5) * 8;
        const float4 a = *(const float4*)(x + (size_t)row * CCC + k);
        const float4 b = *(const float4*)(x + (size_t)row * CCC + k + 4);
        const float e[8] = {a.x, a.y, a.z, a.w, b.x, b.y, b.z, b.w};
        f16x8 vh8, vl8;
        #pragma unroll
        for (int d = 0; d < 8; ++d) {
            const half_t hi = (half_t)e[d];
            vh8[d] = hi; vl8[d] = (half_t)(e[d] - (float)hi);
        }
        const size_t off = ((size_t)f << 9) + lane6 * 8;
        *(f16x8*)(ws + XH_OFF + off) = vh8;
        *(f16x8*)(ws + XL_OFF + off) = vl8;
        return;
    }
    const int u2  = u - 4194304;
    const int mat = u2 >> 15, r = u2 & 32767;
    if (mat < 3) {                                  // ---- Wq/Wk/Wv, 32-layout ----
        const float* src = (mat == 0) ? Wq : (mat == 1) ? Wk : Wv;
        const int f = r >> 6, lane6 = r & 63;
        const int grow32 = f >> 5, ktc = f & 31;
        const int row = grow32 * 32 + (lane6 & 31);
        const int k   = ktc * 16 + (lane6 >> 5) * 8;
        const float4 a = *(const float4*)(src + (size_t)row * CCC + k);
        const float4 b = *(const float4*)(src + (size_t)row * CCC + k + 4);
        const float e[8] = {a.x, a.y, a.z, a.w, b.x, b.y, b.z, b.w};
        f16x8 vh8, vl8;
        #pragma unroll
        for (int d = 0; d < 8; ++d) {
            const half_t hi = (half_t)e[d];
            vh8[d] = hi; vl8[d] = (half_t)(e[d] - (float)hi);
        }
        const size_t off = ((size_t)f << 9) + lane6 * 8;
        half_t* dh = ws + W_OFF + (size_t)(mat * 2) * WPL;
        *(f16x8*)(dh + off) = vh8;
        if (mat < 2) *(f16x8*)(dh + WPL + off) = vl8;   // lo plane for q,k only
        return;
    }
    // ---- Wo, 16-layout ----
    const int gr = r >> 10, v = r & 1023;
    const int ktc = v >> 6, chunk = (v >> 4) & 3, i = v & 15;
    const int row = gr * 16 + i, col = ktc * 32 + chunk * 8;
    const float4 a = *(const float4*)(Wo + (size_t)row * CCC + col);
    const float4 b = *(const float4*)(Wo + (size_t)row * CCC + col + 4);
    const float e[8] = {a.x, a.y, a.z, a.w, b.x, b.y, b.z, b.w};
    f16x8 vh8;
    #pragma unroll
    for (int d = 0; d < 8; ++d) vh8[d] = (half_t)e[d];
    *(f16x8*)(ws + W_OFF + 5 * WPL + blk_off16(row, col)) = vh8;
}

// ---------------------------------------------------------------------------
// k1: QKV projection via fp16x2 32x32x16 MFMA (Q:3,K:3,V:1) + spiking attn.
// INTRA-WAVE SW PIPELINE: double-buffered register frag sets; ds_reads for
// kt+1 issue async and complete UNDER the MFMAs of kt. Counted-vmcnt staging,
// 2 barriers/kt, 3 blocks/CU.
// ---------------------------------------------------------------------------
__global__ __launch_bounds__(256, 3)
void k1_mfma(const half_t* __restrict__ ws,
             const float* __restrict__ bq, const float* __restrict__ bk,
             const float* __restrict__ bv,
             half_t* __restrict__ acth)
{
    __shared__ __align__(16) char smem[52224];

    const int tid  = threadIdx.x;
    const int lane = tid & 63;
    const int wv   = tid >> 6;
    const int rg   = wv >> 1;        // row half: 64 rows
    const int cg   = wv & 1;         // col half: 32 cols
    const int l31  = lane & 31;
    const int l5   = lane >> 5;

    const int xcd  = blockIdx.x & 7;
    const int rest = blockIdx.x >> 3;
    const int h    = rest & 7;
    const int tg   = rest >> 3;
    const int p0   = (tg * 8 + xcd) * 32;

    // ---- staging issue list: 18 frags/kt/block, waves get [5,5,4,4] ----
    const int cnt  = (wv < 2) ? 5 : 4;
    const int base = (wv < 2) ? wv * 5 : 2 + wv * 4;
    const half_t* gb[5]; int lo_[5];
    #pragma unroll
    for (int ii = 0; ii < 5; ++ii) {
        const int i = base + ii;
        size_t eoff; int loff;
        if (i < 8) {            // X frag: t = i>>1, plane = i&1
            const int t = i >> 1, pl = i & 1;
            const size_t rbg = (size_t)t * 512 + (p0 >> 5);
            eoff = (pl ? XL_OFF : XH_OFF) + (rbg << 14) + lane * 8;
            loff = i * 1024;
        } else {                // W frag: s = i-8: plane = s>>1, cb = s&1
            const int s = (i - 8) & 15;
            const int plw = (s >> 1) > 4 ? 4 : (s >> 1), cb = s & 1;
            eoff = W_OFF + (size_t)plw * WPL + ((size_t)(h * 2 + cb) << 14) + lane * 8;
            loff = 8192 + s * 1024;
        }
        gb[ii] = ws + eoff;
        lo_[ii] = loff;
    }

#define K1_STAGE(buf, kt) do {                                                  \
    _Pragma("unroll")                                                           \
    for (int ii = 0; ii < 5; ++ii)                                              \
        if (ii < cnt)                                                           \
            __builtin_amdgcn_global_load_lds(                                   \
                (const __attribute__((address_space(1))) void*)(gb[ii] + (size_t)(kt) * 512), \
                (__attribute__((address_space(3))) void*)(smem + (buf) * 18432 + lo_[ii]),    \
                16, 0, 0);                                                      \
    } while (0)

#define VMW_CNT() do { if (cnt == 5) asm volatile("s_waitcnt vmcnt(5)" ::: "memory"); \
                       else          asm volatile("s_waitcnt vmcnt(4)" ::: "memory"); } while (0)
#define VMW_0()   asm volatile("s_waitcnt vmcnt(0)" ::: "memory")
#define LGW_0()   asm volatile("s_waitcnt lgkmcnt(0)" ::: "memory")
#define SCB()     __builtin_amdgcn_sched_barrier(0)
#define SBAR()    __builtin_amdgcn_s_barrier()

    // ---- accumulators (bias init; C/D: col=lane&31, row=(reg&3)+8(reg>>2)+4*l5) ----
    f32x16 accQ[2], accK[2], accV[2];
    {
        const int c0 = h * 64 + cg * 32 + l31;
        const float q0 = bq[c0], k0 = bk[c0], v0 = bv[c0];
        #pragma unroll
        for (int i = 0; i < 16; ++i) {
            accQ[0][i] = q0; accQ[1][i] = q0;
            accK[0][i] = k0; accK[1][i] = k0;
            accV[0][i] = v0; accV[1][i] = v0;
        }
    }

    const int boff = 8192 + cg * 1024 + lane * 16;
    const int t0 = rg * 2, t1 = rg * 2 + 1;
    const int aoff0 = (t0 * 2 + 0) * 1024 + lane * 16;
    const int aoff1 = (t0 * 2 + 1) * 1024 + lane * 16;
    const int aoff2 = (t1 * 2 + 0) * 1024 + lane * 16;
    const int aoff3 = (t1 * 2 + 1) * 1024 + lane * 16;
    const char* bp0 = smem;
    const char* bp1 = smem + 18432;

    // frag register sets (double-buffered)
    f16x8 A0h0,A0l0,A0h1,A0l1,B0qh,B0ql,B0kh,B0kl,B0vh;
    f16x8 A1h0,A1l0,A1h1,A1l1,B1qh,B1ql,B1kh,B1kl,B1vh;

#define LOADSET0(bp) do { A0h0=*(const f16x8*)((bp)+aoff0); A0l0=*(const f16x8*)((bp)+aoff1); \
    A0h1=*(const f16x8*)((bp)+aoff2); A0l1=*(const f16x8*)((bp)+aoff3);                       \
    B0qh=*(const f16x8*)((bp)+boff); B0ql=*(const f16x8*)((bp)+boff+2048);                    \
    B0kh=*(const f16x8*)((bp)+boff+4096); B0kl=*(const f16x8*)((bp)+boff+6144);               \
    B0vh=*(const f16x8*)((bp)+boff+8192); } while (0)
#define LOADSET1(bp) do { A1h0=*(const f16x8*)((bp)+aoff0); A1l0=*(const f16x8*)((bp)+aoff1); \
    A1h1=*(const f16x8*)((bp)+aoff2); A1l1=*(const f16x8*)((bp)+aoff3);                       \
    B1qh=*(const f16x8*)((bp)+boff); B1ql=*(const f16x8*)((bp)+boff+2048);                    \
    B1kh=*(const f16x8*)((bp)+boff+4096); B1kl=*(const f16x8*)((bp)+boff+6144);               \
    B1vh=*(const f16x8*)((bp)+boff+8192); } while (0)
#define MM0() do {                                   \
    accQ[0]=MFMA32(A0h0,B0qh,accQ[0]); accQ[1]=MFMA32(A0h1,B0qh,accQ[1]);  \
    accK[0]=MFMA32(A0h0,B0kh,accK[0]); accK[1]=MFMA32(A0h1,B0kh,accK[1]);  \
    accV[0]=MFMA32(A0h0,B0vh,accV[0]); accV[1]=MFMA32(A0h1,B0vh,accV[1]);  \
    accQ[0]=MFMA32(A0h0,B0ql,accQ[0]); accQ[1]=MFMA32(A0h1,B0ql,accQ[1]);  \
    accK[0]=MFMA32(A0h0,B0kl,accK[0]); accK[1]=MFMA32(A0h1,B0kl,accK[1]);  \
    accQ[0]=MFMA32(A0l0,B0qh,accQ[0]); accQ[1]=MFMA32(A0l1,B0qh,accQ[1]);  \
    accK[0]=MFMA32(A0l0,B0kh,accK[0]); accK[1]=MFMA32(A0l1,B0kh,accK[1]);  \
    } while (0)
#define MM1() do {                                   \
    accQ[0]=MFMA32(A1h0,B1qh,accQ[0]); accQ[1]=MFMA32(A1h1,B1qh,accQ[1]);  \
    accK[0]=MFMA32(A1h0,B1kh,accK[0]); accK[1]=MFMA32(A1h1,B1kh,accK[1]);  \
    accV[0]=MFMA32(A1h0,B1vh,accV[0]); accV[1]=MFMA32(A1h1,B1vh,accV[1]);  \
    accQ[0]=MFMA32(A1h0,B1ql,accQ[0]); accQ[1]=MFMA32(A1h1,B1ql,accQ[1]);  \
    accK[0]=MFMA32(A1h0,B1kl,accK[0]); accK[1]=MFMA32(A1h1,B1kl,accK[1]);  \
    accQ[0]=MFMA32(A1l0,B1qh,accQ[0]); accQ[1]=MFMA32(A1l1,B1qh,accQ[1]);  \
    accK[0]=MFMA32(A1l0,B1kh,accK[0]); accK[1]=MFMA32(A1l1,B1kh,accK[1]);  \
    } while (0)

    // ---- prologue: stage kt=0,1; read set0 from buf0 ----
    K1_STAGE(0, 0);
    K1_STAGE(1, 1);
    VMW_CNT();                  // stage(0) landed (stage(1) still in flight)
    SCB();
    SBAR();
    LOADSET0(bp0);              // async ds_reads for kt=0

    #pragma unroll 1
    for (int kt = 0; kt < NK1; kt += 2) {
        // ===== even: compute kt (set0), prefetch kt+1 (set1) =====
        LGW_0(); SCB();          // set0 regs valid; my reads of buf0 done
        SBAR();                  // ALL waves done reading buf0
        if (kt + 2 < NK1) K1_STAGE(0, kt + 2);
        if (kt + 2 < NK1) { VMW_CNT(); } else { VMW_0(); }   // stage(kt+1) landed
        SCB();
        SBAR();                  // buf1 (kt+1) ready for all
        LOADSET1(bp1);           // async; completes under MM0
        __builtin_amdgcn_s_setprio(1);
        MM0();
        __builtin_amdgcn_s_setprio(0);

        // ===== odd: compute kt+1 (set1), prefetch kt+2 (set0) =====
        LGW_0(); SCB();          // set1 regs valid; buf1 reads done
        SBAR();
        if (kt + 3 < NK1) K1_STAGE(1, kt + 3);
        if (kt + 2 < NK1) {
            if (kt + 3 < NK1) { VMW_CNT(); } else { VMW_0(); }
            SCB();
            SBAR();              // buf0 (kt+2) ready
            LOADSET0(bp0);       // async; completes under MM1
        }
        __builtin_amdgcn_s_setprio(1);
        MM1();
        __builtin_amdgcn_s_setprio(0);
    }

    // ---- attention epilogue (two 16-token passes; LDS overlay) ----
    __syncthreads();
    float* qa = (float*)smem;            // [64][68]
    float* ka = qa + 4352;
    float* va = qa + 8704;

    const int ar  = tid >> 2;            // 0..63 = t*16 + jj
    const int t_  = ar >> 4;
    const int jj  = ar & 15;
    const int sub = tid & 3;

    #pragma unroll
    for (int hh = 0; hh < 2; ++hh) {
        #pragma unroll
        for (int rf = 0; rf < 2; ++rf) {
            const int t = rg * 2 + rf;
            #pragma unroll
            for (int rr = 0; rr < 8; ++rr) {
                const int reg = hh * 8 + rr;
                const int j2  = (rr & 3) + 8 * (rr >> 2) + 4 * l5;   // 0..15
                const int idx = (t * 16 + j2) * 68 + cg * 32 + l31;
                qa[idx] = accQ[rf][reg];
                ka[idx] = accK[rf][reg];
                va[idx] = accV[rf][reg];
            }
        }
        __syncthreads();

        const float* qp = qa + ar * 68 + sub * 16;
        const float4 q0 = *(const float4*)(qp);
        const float4 q1 = *(const float4*)(qp + 4);
        const float4 q2 = *(const float4*)(qp + 8);
        const float4 q3 = *(const float4*)(qp + 12);
        float sc[4];
        #pragma unroll
        for (int ss = 0; ss < 4; ++ss) {
            const float* kp = ka + (ss * 16 + jj) * 68 + sub * 16;
            const float4 k0 = *(const float4*)(kp);
            const float4 k1 = *(const float4*)(kp + 4);
            const float4 k2 = *(const float4*)(kp + 8);
            const float4 k3 = *(const float4*)(kp + 12);
            float p = q0.x*k0.x + q0.y*k0.y + q0.z*k0.z + q0.w*k0.w
                    + q1.x*k1.x + q1.y*k1.y + q1.z*k1.z + q1.w*k1.w
                    + q2.x*k2.x + q2.y*k2.y + q2.z*k2.z + q2.w*k2.w
                    + q3.x*k3.x + q3.y*k3.y + q3.z*k3.z + q3.w*k3.w;
            p += __shfl_xor(p, 1);
            p += __shfl_xor(p, 2);
            sc[ss] = p;      // spike <=> (dot/8)/2 >= 1 <=> dot >= 16 (exact)
        }
        float o[16];
        #pragma unroll
        for (int d = 0; d < 16; ++d) o[d] = 0.f;
        #pragma unroll
        for (int ss = 0; ss < 4; ++ss) {
            if (sc[ss] >= 16.0f) {
                const float* vp = va + (ss * 16 + jj) * 68 + sub * 16;
                const float4 v0 = *(const float4*)(vp);
                const float4 v1 = *(const float4*)(vp + 4);
                const float4 v2 = *(const float4*)(vp + 8);
                const float4 v3 = *(const float4*)(vp + 12);
                o[0]+=v0.x; o[1]+=v0.y; o[2]+=v0.z;  o[3]+=v0.w;
                o[4]+=v1.x; o[5]+=v1.y; o[6]+=v1.z;  o[7]+=v1.w;
                o[8]+=v2.x; o[9]+=v2.y; o[10]+=v2.z; o[11]+=v2.w;
                o[12]+=v3.x;o[13]+=v3.y;o[14]+=v3.z; o[15]+=v3.w;
            }
        }
        // store act (fp16, 16-frag blocked layout for k2)
        f16x8 o0, o1;
        #pragma unroll
        for (int d = 0; d < 8; ++d) { o0[d] = (half_t)o[d]; o1[d] = (half_t)o[d + 8]; }
        const int grow = t_ * 1024 + (p0 >> 4) + hh;
        const int colb = h * 64 + sub * 16;
        const size_t cbase = ((size_t)(grow * 16 + (colb >> 5))) << 9;
        const int c0 = (colb >> 3) & 3;
        *(f16x8*)(acth + cbase + (size_t)((c0       * 16 + jj) << 3)) = o0;
        *(f16x8*)(acth + cbase + (size_t)(((c0 + 1) * 16 + jj) << 3)) = o1;
        __syncthreads();
    }
#undef K1_STAGE
#undef LOADSET0
#undef LOADSET1
#undef MM0
#undef MM1
}

// ---------------------------------------------------------------------------
// k2: out = act @ Wo^T + bo, fp16 16x16x32 MFMA, intra-wave SW pipeline.
// ---------------------------------------------------------------------------
__global__ __launch_bounds__(256, 3)
void k2_gemm(const half_t* __restrict__ acth, const half_t* __restrict__ oh,
             const float* __restrict__ bo, float* __restrict__ out)
{
    __shared__ __align__(16) char smem[32768];

    const int tid  = threadIdx.x;
    const int lane = tid & 63;
    const int wv   = tid >> 6;
    const int wr   = wv >> 1, wc = wv & 1;
    const int l15  = lane & 15, l4 = lane >> 4;
    const int bn   = (blockIdx.x & 3) * 128;
    const int bm   = (blockIdx.x >> 2) * 128;

    const half_t* gb[4]; int lo_[4];
    #pragma unroll
    for (int ii = 0; ii < 4; ++ii) {
        const int i = wv * 4 + ii;
        if (i < 8) {
            const int grow = (bm >> 4) + i;
            gb[ii] = acth + ((size_t)grow << 13) + lane * 8;
            lo_[ii] = i * 1024;
        } else {
            const int fb = i - 8;
            const int grow = (bn >> 4) + fb;
            gb[ii] = oh + ((size_t)grow << 13) + lane * 8;
            lo_[ii] = 8192 + fb * 1024;
        }
    }

#define K2_STAGE(buf, kt) do {                                                  \
    _Pragma("unroll")                                                           \
    for (int ii = 0; ii < 4; ++ii)                                              \
        __builtin_amdgcn_global_load_lds(                                       \
            (const __attribute__((address_space(1))) void*)(gb[ii] + (size_t)(kt) * 512), \
            (__attribute__((address_space(3))) void*)(smem + (buf) * 16384 + lo_[ii]),    \
            16, 0, 0);                                                          \
    } while (0)

    f32x4 acc[4][4];
    #pragma unroll
    for (int rf = 0; rf < 4; ++rf)
        #pragma unroll
        for (int cf = 0; cf < 4; ++cf) acc[rf][cf] = f32x4{0.f, 0.f, 0.f, 0.f};

    const char* bp0 = smem;
    const char* bp1 = smem + 16384;
    f16x8 A0[4], B0[4], A1[4], B1[4];

#define LOADS2_0(bp) do {                                                      \
    _Pragma("unroll")                                                          \
    for (int f = 0; f < 4; ++f) {                                              \
        A0[f] = *(const f16x8*)((bp) + (wr * 4 + f) * 1024 + lane * 16);       \
        B0[f] = *(const f16x8*)((bp) + 8192 + (wc * 4 + f) * 1024 + lane * 16);\
    } } while (0)
#define LOADS2_1(bp) do {                                                      \
    _Pragma("unroll")                                                          \
    for (int f = 0; f < 4; ++f) {                                              \
        A1[f] = *(const f16x8*)((bp) + (wr * 4 + f) * 1024 + lane * 16);       \
        B1[f] = *(const f16x8*)((bp) + 8192 + (wc * 4 + f) * 1024 + lane * 16);\
    } } while (0)
#define MM2_0() do {                                                           \
    _Pragma("unroll")                                                          \
    for (int rf = 0; rf < 4; ++rf)                                             \
        _Pragma("unroll")                                                      \
        for (int cf = 0; cf < 4; ++cf)                                         \
            acc[rf][cf] = MFMA16(A0[rf], B0[cf], acc[rf][cf]);                 \
    } while (0)
#define MM2_1() do {                                                           \
    _Pragma("unroll")                                                          \
    for (int rf = 0; rf < 4; ++rf)                                             \
        _Pragma("unroll")                                                      \
        for (int cf = 0; cf < 4; ++cf)                                         \
            acc[rf][cf] = MFMA16(A1[rf], B1[cf], acc[rf][cf]);                 \
    } while (0)

    K2_STAGE(0, 0);
    K2_STAGE(1, 1);
    asm volatile("s_waitcnt vmcnt(4)" ::: "memory");
    __builtin_amdgcn_sched_barrier(0);
    __builtin_amdgcn_s_barrier();
    LOADS2_0(bp0);

    #pragma unroll 1
    for (int kt = 0; kt < NK2; kt += 2) {
        // even: compute kt (set0), prefetch kt+1 (set1)
        asm volatile("s_waitcnt lgkmcnt(0)" ::: "memory");
        __builtin_amdgcn_sched_barrier(0);
        __builtin_amdgcn_s_barrier();
        if (kt + 2 < NK2) K2_STAGE(0, kt + 2);
        if (kt + 2 < NK2) asm volatile("s_waitcnt vmcnt(4)" ::: "memory");
        else              asm volatile("s_waitcnt vmcnt(0)" ::: "memory");
        __builtin_amdgcn_sched_barrier(0);
        __builtin_amdgcn_s_barrier();
        LOADS2_1(bp1);
        __builtin_amdgcn_s_setprio(1);
        MM2_0();
        __builtin_amdgcn_s_setprio(0);

        // odd: compute kt+1 (set1), prefetch kt+2 (set0)
        asm volatile("s_waitcnt lgkmcnt(0)" ::: "memory");
        __builtin_amdgcn_sched_barrier(0);
        __builtin_amdgcn_s_barrier();
        if (kt + 3 < NK2) K2_STAGE(1, kt + 3);
        if (kt + 2 < NK2) {
            if (kt + 3 < NK2) asm volatile("s_waitcnt vmcnt(4)" ::: "memory");
            else              asm volatile("s_waitcnt vmcnt(0)" ::: "memory");
            __builtin_amdgcn_sched_barrier(0);
            __builtin_amdgcn_s_barrier();
            LOADS2_0(bp0);
        }
        __builtin_amdgcn_s_setprio(1);
        MM2_1();
        __builtin_amdgcn_s_setprio(0);
    }

    float bo4[4];
    #pragma unroll
    for (int cf = 0; cf < 4; ++cf) bo4[cf] = bo[bn + (wc * 4 + cf) * 16 + l15];

    #pragma unroll
    for (int rf = 0; rf < 4; ++rf) {
        const int row0 = bm + (wr * 4 + rf) * 16 + l4 * 4;
        #pragma unroll
        for (int cf = 0; cf < 4; ++cf) {
            const int col = bn + (wc * 4 + cf) * 16 + l15;
            #pragma unroll
            for (int r = 0; r < 4; ++r)
                out[(size_t)(row0 + r) * CCC + col] = acc[rf][cf][r] + bo4[cf];
        }
    }
#undef K2_STAGE
#undef LOADS2_0
#undef LOADS2_1
#undef MM2_0
#undef MM2_1
}

// ---------------------------------------------------------------------------
extern "C" void kernel_launch(void* const* d_in, const int* in_sizes, int n_in,
                              void* d_out, int out_size, void* d_ws, size_t ws_size,
                              hipStream_t stream)
{
    const float* x  = (const float*)d_in[0];
    const float* Wq = (const float*)d_in[1];
    const float* bq = (const float*)d_in[2];
    const float* Wk = (const float*)d_in[3];
    const float* bk = (const float*)d_in[4];
    const float* Wv = (const float*)d_in[5];
    const float* bv = (const float*)d_in[6];
    const float* Wo = (const float*)d_in[7];
    const float* bo = (const float*)d_in[8];

    half_t* ws   = (half_t*)d_ws;
    half_t* acth = ws + ACT_OFF;
    float*  out  = (float*)d_out;

    hipLaunchKernelGGL(k0_split, dim3(16896), dim3(256), 0, stream,
                       x, Wq, Wk, Wv, Wo, ws);
    hipLaunchKernelGGL(k1_mfma, dim3(4096), dim3(256), 0, stream,
                       ws, bq, bk, bv, acth);
    hipLaunchKernelGGL(k2_gemm, dim3(2048), dim3(256), 0, stream,
                       acth, ws + W_OFF + 5*WPL, bo, out);
}

// Round 10
// 371.573 us; speedup vs baseline: 2.6225x; 2.6225x over previous
//
#include <hip/hip_runtime.h>

#define PTOT  16384
#define CCC   512
#define HHH   8
#define NK1   32                 /* k1: 512/16 k-steps */
#define NK2   16                 /* k2: 512/32 k-steps */

typedef __attribute__((ext_vector_type(4)))  float f32x4;
typedef __attribute__((ext_vector_type(16))) float f32x16;
typedef _Float16 half_t;
typedef __attribute__((ext_vector_type(8))) _Float16 f16x8;

#define MFMA16(a,b,c) __builtin_amdgcn_mfma_f32_16x16x32_f16(a,b,c,0,0,0)
#define MFMA32(a,b,c) __builtin_amdgcn_mfma_f32_32x32x16_f16(a,b,c,0,0,0)

// ---- ws plane layout (half elements) ----
#define XH_OFF   ((size_t)0)
#define XL_OFF   ((size_t)33554432)
#define ACT_OFF  ((size_t)67108864)
#define W_OFF    ((size_t)100663296)
#define WPL      ((size_t)262144)
// W plane order: 0 qh, 1 ql, 2 kh, 3 kl, 4 vh, 5 oh

#define VMW(n)  asm volatile("s_waitcnt vmcnt(" #n ")" ::: "memory")
#define LGW0()  asm volatile("s_waitcnt lgkmcnt(0)" ::: "memory")
#define SCB()   __builtin_amdgcn_sched_barrier(0)
#define SBAR()  __builtin_amdgcn_s_barrier()

// 16-row frag layout (act plane + Wo plane; k2 consumes via 16x16x32 MFMA)
__device__ __forceinline__ size_t blk_off16(int row, int col) {
    return ((size_t)((row >> 4) * 16 + (col >> 5)) << 9)
         + (size_t)(((((col >> 3) & 3) * 16) + (row & 15)) << 3) + (col & 7);
}

// ---------------------------------------------------------------------------
// k0: split fp32 -> fp16 hi/lo planes (unchanged from rounds 6-9).
// ---------------------------------------------------------------------------
__global__ void k0_split(const float* __restrict__ x,
                         const float* __restrict__ Wq, const float* __restrict__ Wk,
                         const float* __restrict__ Wv, const float* __restrict__ Wo,
                         half_t* __restrict__ ws)
{
    const int u = blockIdx.x * 256 + threadIdx.x;   // 4,325,376 threads
    if (u < 4194304) {                              // ---- x region ----
        const int f = u >> 6, lane6 = u & 63;
        const int grow32 = f >> 5, ktc = f & 31;
        const int row = grow32 * 32 + (lane6 & 31);
        const int k   = ktc * 16 + (lane6 >> 5) * 8;
        const float4 a = *(const float4*)(x + (size_t)row * CCC + k);
        const float4 b = *(const float4*)(x + (size_t)row * CCC + k + 4);
        const float e[8] = {a.x, a.y, a.z, a.w, b.x, b.y, b.z, b.w};
        f16x8 vh8, vl8;
        #pragma unroll
        for (int d = 0; d < 8; ++d) {
            const half_t hi = (half_t)e[d];
            vh8[d] = hi; vl8[d] = (half_t)(e[d] - (float)hi);
        }
        const size_t off = ((size_t)f << 9) + lane6 * 8;
        *(f16x8*)(ws + XH_OFF + off) = vh8;
        *(f16x8*)(ws + XL_OFF + off) = vl8;
        return;
    }
    const int u2  = u - 4194304;
    const int mat = u2 >> 15, r = u2 & 32767;
    if (mat < 3) {                                  // ---- Wq/Wk/Wv, 32-layout ----
        const float* src = (mat == 0) ? Wq : (mat == 1) ? Wk : Wv;
        const int f = r >> 6, lane6 = r & 63;
        const int grow32 = f >> 5, ktc = f & 31;
        const int row = grow32 * 32 + (lane6 & 31);
        const int k   = ktc * 16 + (lane6 >> 5) * 8;
        const float4 a = *(const float4*)(src + (size_t)row * CCC + k);
        const float4 b = *(const float4*)(src + (size_t)row * CCC + k + 4);
        const float e[8] = {a.x, a.y, a.z, a.w, b.x, b.y, b.z, b.w};
        f16x8 vh8, vl8;
        #pragma unroll
        for (int d = 0; d < 8; ++d) {
            const half_t hi = (half_t)e[d];
            vh8[d] = hi; vl8[d] = (half_t)(e[d] - (float)hi);
        }
        const size_t off = ((size_t)f << 9) + lane6 * 8;
        half_t* dh = ws + W_OFF + (size_t)(mat * 2) * WPL;
        *(f16x8*)(dh + off) = vh8;
        if (mat < 2) *(f16x8*)(dh + WPL + off) = vl8;   // lo plane for q,k only
        return;
    }
    // ---- Wo, 16-layout ----
    const int gr = r >> 10, v = r & 1023;
    const int ktc = v >> 6, chunk = (v >> 4) & 3, i = v & 15;
    const int row = gr * 16 + i, col = ktc * 32 + chunk * 8;
    const float4 a = *(const float4*)(Wo + (size_t)row * CCC + col);
    const float4 b = *(const float4*)(Wo + (size_t)row * CCC + col + 4);
    const float e[8] = {a.x, a.y, a.z, a.w, b.x, b.y, b.z, b.w};
    f16x8 vh8;
    #pragma unroll
    for (int d = 0; d < 8; ++d) vh8[d] = (half_t)e[d];
    *(f16x8*)(ws + W_OFF + 5 * WPL + blk_off16(row, col)) = vh8;
}

// ---------------------------------------------------------------------------
// k1: QKV projection (fp16x2 32x32x16 MFMA, Q:3,K:3,V:1) + spiking attn.
// Hybrid routing (X via LDS, W global->reg). FIXED pipeline order: the B-reg
// set for kt+2 is loaded AFTER MM consumes kt's values; completion of B(kt)
// is guaranteed by the counted vmcnt(7) at the END of the previous half-step.
// ---------------------------------------------------------------------------
__global__ __launch_bounds__(256, 2)
void k1_mfma(const half_t* __restrict__ ws,
             const float* __restrict__ bq, const float* __restrict__ bk,
             const float* __restrict__ bv,
             half_t* __restrict__ acth)
{
    __shared__ __align__(16) char smem[52224];

    const int tid  = threadIdx.x;
    const int lane = tid & 63;
    const int wv   = tid >> 6;
    const int rg   = wv >> 1;        // row half: 64 rows (t = 2rg, 2rg+1)
    const int cg   = wv & 1;         // col half: 32 cols
    const int l31  = lane & 31;
    const int l5   = lane >> 5;

    const int xcd  = blockIdx.x & 7;
    const int rest = blockIdx.x >> 3;
    const int h    = rest & 7;
    const int tg   = rest >> 3;
    const int p0   = (tg * 8 + xcd) * 32;

    // ---- X staging: 8 slots (t*2+pl) x 1KB; wave wv stages t=wv (2 issues) ----
    const half_t* gx0 = ws + XH_OFF + ((size_t)(wv * 512 + (p0 >> 5)) << 14) + lane * 8;
    const half_t* gx1 = ws + XL_OFF + ((size_t)(wv * 512 + (p0 >> 5)) << 14) + lane * 8;
    const int lo0 = (wv * 2) * 1024;
    const int lo1 = (wv * 2 + 1) * 1024;

#define K1_STAGE(buf, kt) do {                                                  \
    __builtin_amdgcn_global_load_lds(                                           \
        (const __attribute__((address_space(1))) void*)(gx0 + (size_t)(kt) * 512), \
        (__attribute__((address_space(3))) void*)(smem + (buf) * 8192 + lo0), 16, 0, 0); \
    __builtin_amdgcn_global_load_lds(                                           \
        (const __attribute__((address_space(1))) void*)(gx1 + (size_t)(kt) * 512), \
        (__attribute__((address_space(3))) void*)(smem + (buf) * 8192 + lo1), 16, 0, 0); \
    } while (0)

    // ---- B streams (global->reg, coalesced 1KB/wave, L2-resident) ----
    const size_t grB = ((size_t)(h * 2 + cg) << 14) + lane * 8;
    const half_t* pBqh = ws + W_OFF + 0 * WPL + grB;
    const half_t* pBql = ws + W_OFF + 1 * WPL + grB;
    const half_t* pBkh = ws + W_OFF + 2 * WPL + grB;
    const half_t* pBkl = ws + W_OFF + 3 * WPL + grB;
    const half_t* pBvh = ws + W_OFF + 4 * WPL + grB;

    f16x8 B0qh, B0ql, B0kh, B0kl, B0vh;      // set 0 (even kt)
    f16x8 B1qh, B1ql, B1kh, B1kl, B1vh;      // set 1 (odd kt)

#define LOADB0(kt) do {                                                         \
    B0qh = *(const f16x8*)(pBqh + (size_t)(kt) * 512);                          \
    B0ql = *(const f16x8*)(pBql + (size_t)(kt) * 512);                          \
    B0kh = *(const f16x8*)(pBkh + (size_t)(kt) * 512);                          \
    B0kl = *(const f16x8*)(pBkl + (size_t)(kt) * 512);                          \
    B0vh = *(const f16x8*)(pBvh + (size_t)(kt) * 512); } while (0)
#define LOADB1(kt) do {                                                         \
    B1qh = *(const f16x8*)(pBqh + (size_t)(kt) * 512);                          \
    B1ql = *(const f16x8*)(pBql + (size_t)(kt) * 512);                          \
    B1kh = *(const f16x8*)(pBkh + (size_t)(kt) * 512);                          \
    B1kl = *(const f16x8*)(pBkl + (size_t)(kt) * 512);                          \
    B1vh = *(const f16x8*)(pBvh + (size_t)(kt) * 512); } while (0)

    // ---- accumulators (bias init; C/D: col=lane&31, row=(reg&3)+8(reg>>2)+4*l5) ----
    f32x16 accQ[2], accK[2], accV[2];
    {
        const int c0 = h * 64 + cg * 32 + l31;
        const float q0 = bq[c0], k0 = bk[c0], v0 = bv[c0];
        #pragma unroll
        for (int i = 0; i < 16; ++i) {
            accQ[0][i] = q0; accQ[1][i] = q0;
            accK[0][i] = k0; accK[1][i] = k0;
            accV[0][i] = v0; accV[1][i] = v0;
        }
    }

    // A frags (re-read from LDS each half-step)
    f16x8 Ah0, Al0, Ah1, Al1;
    const int as0 = (rg * 4 + 0) * 1024 + lane * 16;
    const int as1 = (rg * 4 + 1) * 1024 + lane * 16;
    const int as2 = (rg * 4 + 2) * 1024 + lane * 16;
    const int as3 = (rg * 4 + 3) * 1024 + lane * 16;

#define DSREAD(bp) do {                                                         \
    Ah0 = *(const f16x8*)((bp) + as0); Al0 = *(const f16x8*)((bp) + as1);       \
    Ah1 = *(const f16x8*)((bp) + as2); Al1 = *(const f16x8*)((bp) + as3); } while (0)

#define MM(Bqh,Bql,Bkh,Bkl,Bvh) do {                                            \
    accQ[0]=MFMA32(Ah0,Bqh,accQ[0]); accQ[1]=MFMA32(Ah1,Bqh,accQ[1]);           \
    accK[0]=MFMA32(Ah0,Bkh,accK[0]); accK[1]=MFMA32(Ah1,Bkh,accK[1]);           \
    accV[0]=MFMA32(Ah0,Bvh,accV[0]); accV[1]=MFMA32(Ah1,Bvh,accV[1]);           \
    accQ[0]=MFMA32(Ah0,Bql,accQ[0]); accQ[1]=MFMA32(Ah1,Bql,accQ[1]);           \
    accK[0]=MFMA32(Ah0,Bkl,accK[0]); accK[1]=MFMA32(Ah1,Bkl,accK[1]);           \
    accQ[0]=MFMA32(Al0,Bqh,accQ[0]); accQ[1]=MFMA32(Al1,Bqh,accQ[1]);           \
    accK[0]=MFMA32(Al0,Bkh,accK[0]); accK[1]=MFMA32(Al1,Bkh,accK[1]); } while (0)

    const char* bp0 = smem;
    const char* bp1 = smem + 8192;

    // ---- prologue: issue sets for kt=0 and kt=1 (14 vmem in flight) ----
    K1_STAGE(0, 0); LOADB0(0);
    K1_STAGE(1, 1); LOADB1(1);
    VMW(7); SCB();                     // stage(0)+B0(0) complete
    SBAR();

    #pragma unroll 1
    for (int kt = 0; kt < NK1; kt += 2) {
        // ===== even: compute kt from buf0/B0; refill set0 with kt+2 AFTER MM =====
        DSREAD(bp0);
        LGW0(); SCB();
        SBAR();                        // all waves done reading buf0
        if (kt + 2 < NK1) K1_STAGE(0, kt + 2);
        __builtin_amdgcn_s_setprio(1);
        MM(B0qh, B0ql, B0kh, B0kl, B0vh);     // consumes B0@kt (already waited)
        __builtin_amdgcn_s_setprio(0);
        if (kt + 2 < NK1) { LOADB0(kt + 2); VMW(7); }  // drain stage(kt+1)+B1(kt+1)
        else              { VMW(0); }
        SCB();
        SBAR();                        // buf1 (kt+1) visible; B1@kt+1 valid

        // ===== odd: compute kt+1 from buf1/B1; refill set1 with kt+3 AFTER MM =====
        DSREAD(bp1);
        LGW0(); SCB();
        SBAR();                        // all waves done reading buf1
        if (kt + 3 < NK1) K1_STAGE(1, kt + 3);
        __builtin_amdgcn_s_setprio(1);
        MM(B1qh, B1ql, B1kh, B1kl, B1vh);     // consumes B1@kt+1
        __builtin_amdgcn_s_setprio(0);
        if (kt + 3 < NK1) { LOADB1(kt + 3); VMW(7); }  // drain stage(kt+2)+B0(kt+2)
        else if (kt + 2 < NK1) { VMW(0); }
        else              { VMW(0); }
        SCB();
        SBAR();                        // buf0 (kt+2) visible; B0@kt+2 valid
    }

    // ---- attention epilogue (two 16-token passes; LDS overlay) ----
    __syncthreads();
    float* qa = (float*)smem;            // [64][68]
    float* ka = qa + 4352;
    float* va = qa + 8704;

    const int ar  = tid >> 2;            // 0..63 = t*16 + jj
    const int t_  = ar >> 4;
    const int jj  = ar & 15;
    const int sub = tid & 3;

    #pragma unroll
    for (int hh = 0; hh < 2; ++hh) {
        #pragma unroll
        for (int rf = 0; rf < 2; ++rf) {
            const int t = rg * 2 + rf;
            #pragma unroll
            for (int rr = 0; rr < 8; ++rr) {
                const int reg = hh * 8 + rr;
                const int j2  = (rr & 3) + 8 * (rr >> 2) + 4 * l5;   // 0..15
                const int idx = (t * 16 + j2) * 68 + cg * 32 + l31;
                qa[idx] = accQ[rf][reg];
                ka[idx] = accK[rf][reg];
                va[idx] = accV[rf][reg];
            }
        }
        __syncthreads();

        const float* qp = qa + ar * 68 + sub * 16;
        const float4 q0 = *(const float4*)(qp);
        const float4 q1 = *(const float4*)(qp + 4);
        const float4 q2 = *(const float4*)(qp + 8);
        const float4 q3 = *(const float4*)(qp + 12);
        float sc[4];
        #pragma unroll
        for (int ss = 0; ss < 4; ++ss) {
            const float* kp = ka + (ss * 16 + jj) * 68 + sub * 16;
            const float4 k0 = *(const float4*)(kp);
            const float4 k1 = *(const float4*)(kp + 4);
            const float4 k2 = *(const float4*)(kp + 8);
            const float4 k3 = *(const float4*)(kp + 12);
            float p = q0.x*k0.x + q0.y*k0.y + q0.z*k0.z + q0.w*k0.w
                    + q1.x*k1.x + q1.y*k1.y + q1.z*k1.z + q1.w*k1.w
                    + q2.x*k2.x + q2.y*k2.y + q2.z*k2.z + q2.w*k2.w
                    + q3.x*k3.x + q3.y*k3.y + q3.z*k3.z + q3.w*k3.w;
            p += __shfl_xor(p, 1);
            p += __shfl_xor(p, 2);
            sc[ss] = p;      // spike <=> (dot/8)/2 >= 1 <=> dot >= 16 (exact)
        }
        float o[16];
        #pragma unroll
        for (int d = 0; d < 16; ++d) o[d] = 0.f;
        #pragma unroll
        for (int ss = 0; ss < 4; ++ss) {
            if (sc[ss] >= 16.0f) {
                const float* vp = va + (ss * 16 + jj) * 68 + sub * 16;
                const float4 v0 = *(const float4*)(vp);
                const float4 v1 = *(const float4*)(vp + 4);
                const float4 v2 = *(const float4*)(vp + 8);
                const float4 v3 = *(const float4*)(vp + 12);
                o[0]+=v0.x; o[1]+=v0.y; o[2]+=v0.z;  o[3]+=v0.w;
                o[4]+=v1.x; o[5]+=v1.y; o[6]+=v1.z;  o[7]+=v1.w;
                o[8]+=v2.x; o[9]+=v2.y; o[10]+=v2.z; o[11]+=v2.w;
                o[12]+=v3.x;o[13]+=v3.y;o[14]+=v3.z; o[15]+=v3.w;
            }
        }
        // store act (fp16, 16-frag blocked layout for k2)
        f16x8 o0, o1;
        #pragma unroll
        for (int d = 0; d < 8; ++d) { o0[d] = (half_t)o[d]; o1[d] = (half_t)o[d + 8]; }
        const int grow = t_ * 1024 + (p0 >> 4) + hh;
        const int colb = h * 64 + sub * 16;
        const size_t cbase = ((size_t)(grow * 16 + (colb >> 5))) << 9;
        const int c0 = (colb >> 3) & 3;
        *(f16x8*)(acth + cbase + (size_t)((c0       * 16 + jj) << 3)) = o0;
        *(f16x8*)(acth + cbase + (size_t)(((c0 + 1) * 16 + jj) << 3)) = o1;
        __syncthreads();
    }
#undef K1_STAGE
#undef LOADB0
#undef LOADB1
#undef DSREAD
#undef MM
}

// ---------------------------------------------------------------------------
// k2: out = act @ Wo^T + bo, fp16 16x16x32 MFMA. Hybrid routing, fixed order
// (B refill AFTER MM). A via LDS staging, Wo (B) global->reg.
// ---------------------------------------------------------------------------
__global__ __launch_bounds__(256, 3)
void k2_gemm(const half_t* __restrict__ acth, const half_t* __restrict__ oh,
             const float* __restrict__ bo, float* __restrict__ out)
{
    __shared__ __align__(16) char smem[16384];

    const int tid  = threadIdx.x;
    const int lane = tid & 63;
    const int wv   = tid >> 6;
    const int wr   = wv >> 1, wc = wv & 1;
    const int l15  = lane & 15, l4 = lane >> 4;
    const int bn   = (blockIdx.x & 3) * 128;
    const int bm   = (blockIdx.x >> 2) * 128;

    // A staging: 8 slots x 1KB; wave wv stages slots 2wv, 2wv+1
    const half_t* ga0 = acth + ((size_t)((bm >> 4) + 2 * wv)     << 13) + lane * 8;
    const half_t* ga1 = acth + ((size_t)((bm >> 4) + 2 * wv + 1) << 13) + lane * 8;
    const int lo0 = (2 * wv) * 1024, lo1 = (2 * wv + 1) * 1024;

#define K2_STAGE(buf, kt) do {                                                  \
    __builtin_amdgcn_global_load_lds(                                           \
        (const __attribute__((address_space(1))) void*)(ga0 + (size_t)(kt) * 512), \
        (__attribute__((address_space(3))) void*)(smem + (buf) * 8192 + lo0), 16, 0, 0); \
    __builtin_amdgcn_global_load_lds(                                           \
        (const __attribute__((address_space(1))) void*)(ga1 + (size_t)(kt) * 512), \
        (__attribute__((address_space(3))) void*)(smem + (buf) * 8192 + lo1), 16, 0, 0); \
    } while (0)

    // B streams (Wo, 512KB L2-resident)
    const half_t* pB0 = oh + ((size_t)((bn >> 4) + wc * 4 + 0) << 13) + lane * 8;
    const half_t* pB1 = oh + ((size_t)((bn >> 4) + wc * 4 + 1) << 13) + lane * 8;
    const half_t* pB2 = oh + ((size_t)((bn >> 4) + wc * 4 + 2) << 13) + lane * 8;
    const half_t* pB3 = oh + ((size_t)((bn >> 4) + wc * 4 + 3) << 13) + lane * 8;

    f16x8 B0a, B0b, B0c, B0d, B1a, B1b, B1c, B1d;
#define K2LOADB0(kt) do { B0a=*(const f16x8*)(pB0+(size_t)(kt)*512); B0b=*(const f16x8*)(pB1+(size_t)(kt)*512); \
                          B0c=*(const f16x8*)(pB2+(size_t)(kt)*512); B0d=*(const f16x8*)(pB3+(size_t)(kt)*512); } while (0)
#define K2LOADB1(kt) do { B1a=*(const f16x8*)(pB0+(size_t)(kt)*512); B1b=*(const f16x8*)(pB1+(size_t)(kt)*512); \
                          B1c=*(const f16x8*)(pB2+(size_t)(kt)*512); B1d=*(const f16x8*)(pB3+(size_t)(kt)*512); } while (0)

    f32x4 acc[4][4];
    #pragma unroll
    for (int rf = 0; rf < 4; ++rf)
        #pragma unroll
        for (int cf = 0; cf < 4; ++cf) acc[rf][cf] = f32x4{0.f, 0.f, 0.f, 0.f};

    f16x8 A0, A1, A2, A3;
    const int as0 = (wr * 4 + 0) * 1024 + lane * 16;
    const int as1 = (wr * 4 + 1) * 1024 + lane * 16;
    const int as2 = (wr * 4 + 2) * 1024 + lane * 16;
    const int as3 = (wr * 4 + 3) * 1024 + lane * 16;
#define K2DSREAD(bp) do { A0=*(const f16x8*)((bp)+as0); A1=*(const f16x8*)((bp)+as1); \
                          A2=*(const f16x8*)((bp)+as2); A3=*(const f16x8*)((bp)+as3); } while (0)
#define K2MM(Ba,Bb,Bc,Bd) do {                                                  \
    acc[0][0]=MFMA16(A0,Ba,acc[0][0]); acc[0][1]=MFMA16(A0,Bb,acc[0][1]);       \
    acc[0][2]=MFMA16(A0,Bc,acc[0][2]); acc[0][3]=MFMA16(A0,Bd,acc[0][3]);       \
    acc[1][0]=MFMA16(A1,Ba,acc[1][0]); acc[1][1]=MFMA16(A1,Bb,acc[1][1]);       \
    acc[1][2]=MFMA16(A1,Bc,acc[1][2]); acc[1][3]=MFMA16(A1,Bd,acc[1][3]);       \
    acc[2][0]=MFMA16(A2,Ba,acc[2][0]); acc[2][1]=MFMA16(A2,Bb,acc[2][1]);       \
    acc[2][2]=MFMA16(A2,Bc,acc[2][2]); acc[2][3]=MFMA16(A2,Bd,acc[2][3]);       \
    acc[3][0]=MFMA16(A3,Ba,acc[3][0]); acc[3][1]=MFMA16(A3,Bb,acc[3][1]);       \
    acc[3][2]=MFMA16(A3,Bc,acc[3][2]); acc[3][3]=MFMA16(A3,Bd,acc[3][3]); } while (0)

    const char* bp0 = smem;
    const char* bp1 = smem + 8192;

    K2_STAGE(0, 0); K2LOADB0(0);
    K2_STAGE(1, 1); K2LOADB1(1);
    VMW(6); SCB();
    SBAR();

    #pragma unroll 1
    for (int kt = 0; kt < NK2; kt += 2) {
        // even: compute kt (B0), refill B0 with kt+2 AFTER MM
        K2DSREAD(bp0);
        LGW0(); SCB();
        SBAR();
        if (kt + 2 < NK2) K2_STAGE(0, kt + 2);
        __builtin_amdgcn_s_setprio(1);
        K2MM(B0a, B0b, B0c, B0d);
        __builtin_amdgcn_s_setprio(0);
        if (kt + 2 < NK2) { K2LOADB0(kt + 2); VMW(6); }
        else              { VMW(0); }
        SCB();
        SBAR();

        // odd: compute kt+1 (B1), refill B1 with kt+3 AFTER MM
        K2DSREAD(bp1);
        LGW0(); SCB();
        SBAR();
        if (kt + 3 < NK2) K2_STAGE(1, kt + 3);
        __builtin_amdgcn_s_setprio(1);
        K2MM(B1a, B1b, B1c, B1d);
        __builtin_amdgcn_s_setprio(0);
        if (kt + 3 < NK2) { K2LOADB1(kt + 3); VMW(6); }
        else              { VMW(0); }
        SCB();
        SBAR();
    }

    float bo4[4];
    #pragma unroll
    for (int cf = 0; cf < 4; ++cf) bo4[cf] = bo[bn + (wc * 4 + cf) * 16 + l15];

    #pragma unroll
    for (int rf = 0; rf < 4; ++rf) {
        const int row0 = bm + (wr * 4 + rf) * 16 + l4 * 4;
        #pragma unroll
        for (int cf = 0; cf < 4; ++cf) {
            const int col = bn + (wc * 4 + cf) * 16 + l15;
            #pragma unroll
            for (int r = 0; r < 4; ++r)
                out[(size_t)(row0 + r) * CCC + col] = acc[rf][cf][r] + bo4[cf];
        }
    }
#undef K2_STAGE
#undef K2LOADB0
#undef K2LOADB1
#undef K2DSREAD
#undef K2MM
}

// ---------------------------------------------------------------------------
extern "C" void kernel_launch(void* const* d_in, const int* in_sizes, int n_in,
                              void* d_out, int out_size, void* d_ws, size_t ws_size,
                              hipStream_t stream)
{
    const float* x  = (const float*)d_in[0];
    const float* Wq = (const float*)d_in[1];
    const float* bq = (const float*)d_in[2];
    const float* Wk = (const float*)d_in[3];
    const float* bk = (const float*)d_in[4];
    const float* Wv = (const float*)d_in[5];
    const float* bv = (const float*)d_in[6];
    const float* Wo = (const float*)d_in[7];
    const float* bo = (const float*)d_in[8];

    half_t* ws   = (half_t*)d_ws;
    half_t* acth = ws + ACT_OFF;
    float*  out  = (float*)d_out;

    hipLaunchKernelGGL(k0_split, dim3(16896), dim3(256), 0, stream,
                       x, Wq, Wk, Wv, Wo, ws);
    hipLaunchKernelGGL(k1_mfma, dim3(4096), dim3(256), 0, stream,
                       ws, bq, bk, bv, acth);
    hipLaunchKernelGGL(k2_gemm, dim3(2048), dim3(256), 0, stream,
                       acth, ws + W_OFF + 5*WPL, bo, out);
}